// Round 1
// baseline (813.190 us; speedup 1.0000x reference)
//
#include <hip/hip_runtime.h>

typedef _Float16 half8 __attribute__((ext_vector_type(8)));
typedef float f32x4 __attribute__((ext_vector_type(4)));

#define SCOPE __HIP_MEMORY_SCOPE_AGENT

// Problem: B=16, T=64, L=64, H=256. K=2H=512, N=4H=1024.
//
// Tag-in-word protocol (replaces flags + release fences):
//   h published as 8B atomic words: bits 0-15 = h[2w] (f16), 16-31 = h[2w+1] (f16),
//   32-47 = tag (= t of the producing step), 48-63 = 0.
//   Producer: relaxed 8B atomic stores, fire-and-forget (no drain, no fence, no flag).
//   Consumer: polls its own words; tag match <=> payload valid (word atomicity).
//   Backpressure: prog[wg] = latest t whose staging completed (relaxed store after the
//   staging barrier). Producer (l,r) may publish step t (overwriting slot t&1 = step t-2)
//   once all 4 WGs of layer l+1 have prog >= t-2. Sibling reads of h(l,t-2) are implied:
//   being at step t post-staging => siblings published t-1 => they staged t-1 (read t-2).
//
// ws layout (ws_size >= 3 MB proven in round 1):
//   prog[256] int at 0 (init -1)
//   Hw at 64KB: 2 slots * 64 l * 16 b * 128 words * 8B = 2 MB
constexpr size_t OFF_PROG = 0;
constexpr size_t OFF_H    = 65536;
constexpr size_t SLOT_STRIDE = (size_t)64 * 16 * 128;  // words per slot

__device__ __forceinline__ size_t Widx(int l, int b, int wi) {
  return ((size_t)l * 16 + b) * 128 + wi;
}
__device__ __forceinline__ float sigm(float v) { return 1.0f / (1.0f + __expf(-v)); }
__device__ __forceinline__ float tanh_(float v) { return 1.0f - 2.0f / (__expf(2.0f * v) + 1.0f); }

// ---------------- init: prog=-1, slot0 tags invalid, slot1 = h(l,-1) w/ tag 0xFFFF ----
// Must rewrite ALL tags each launch: leftover tags from a previous launch (t=62/63)
// could otherwise satisfy a fresh consumer's tag check with stale data.
__global__ void init_ws(const float* __restrict__ init_state, char* ws) {
  int* prog = (int*)(ws + OFF_PROG);
  unsigned long long* Hw = (unsigned long long*)(ws + OFF_H);
  const int tid = blockIdx.x * 256 + threadIdx.x;  // 65536 threads
  if (tid < 256) prog[tid] = -1;
  for (int e = tid; e < 64 * 16 * 128; e += 65536) {
    const int wi = e & 127, b = (e >> 7) & 15, l = e >> 11;
    Hw[Widx(l, b, wi)] = 0xFFFE00000000ULL;  // slot0: tag 0xFFFE (never matches)
    union { _Float16 f; unsigned short s; } h0, h1;
    h0.f = (_Float16)init_state[((l * 2 + 1) * 16 + b) * 256 + 2 * wi];
    h1.f = (_Float16)init_state[((l * 2 + 1) * 16 + b) * 256 + 2 * wi + 1];
    Hw[SLOT_STRIDE + Widx(l, b, wi)] =
        (unsigned long long)h0.s | ((unsigned long long)h1.s << 16) | (0xFFFFULL << 32);
  }
}

// ---------------- main: 256 WGs = (layer l = wg>>2, slice r = wg&3) ----------------
__global__ __launch_bounds__(256, 1) void lstm_mfma(
    const float* __restrict__ x, const float* __restrict__ init_state,
    const float* __restrict__ W, const float* __restrict__ bias,
    float* __restrict__ out, char* ws) {
  int* prog = (int*)(ws + OFF_PROG);
  unsigned long long* Hw = (unsigned long long*)(ws + OFF_H);

  const int tid = threadIdx.x;
  const int wg = blockIdx.x;
  const int l = wg >> 2, r = wg & 3;
  const int wv = tid >> 6, lane = tid & 63;

  __shared__ alignas(16) _Float16 aLds[16 * 64 * 8];  // A-frags: [kb][lane][8], 16 KB
  __shared__ alignas(16) float zLds[16 * 260];        // z transpose, 16.6 KB
  __shared__ unsigned short hLds[16 * 64];            // nh f16 bits, 2 KB

  // ---- W slice -> registers (unchanged) ----
  half8 wreg[64];
#pragma unroll
  for (int q = 0; q < 4; ++q) {
    const int nl = (wv * 4 + q) * 16 + (lane & 15);
    const int col = (nl & 3) * 256 + r * 64 + (nl >> 2);
#pragma unroll
    for (int kb = 0; kb < 16; ++kb) {
      const int k0 = kb * 32 + (lane >> 4) * 8;
      const float* src = W + (size_t)k0 * 1024 + col;
      half8 hv;
#pragma unroll
      for (int jj = 0; jj < 8; ++jj) hv[jj] = (_Float16)src[(size_t)jj * 1024];
      wreg[q * 16 + kb] = hv;
    }
  }

  // ---- per-thread epilogue identity (unchanged) ----
  const int hu = tid & 63, b4 = tid >> 6;
  const int gu = r * 64 + hu;
  float creg[4];
#pragma unroll
  for (int bb = 0; bb < 4; ++bb)
    creg[bb] = init_state[((l * 2 + 0) * 16 + (b4 * 4 + bb)) * 256 + gu];
  const float bi_ = bias[0 * 256 + gu], bj_ = bias[1 * 256 + gu];
  const float bf_ = bias[2 * 256 + gu], bo_ = bias[3 * 256 + gu];

  // ---- staging entry invariants: entry i: e=i*256+tid -> (kb,ln,m,k0) ----
  // i<2: K-low half (input = x or h(l-1,t));  i>=2: K-high half (own h(l,t-1)).
  int kbA[4], lnA[4];
  size_t wbase[4];
#pragma unroll
  for (int i = 0; i < 4; ++i) {
    const int e = i * 256 + tid, kb = e >> 6, ln = e & 63;
    const int m = ln & 15, k0 = kb * 32 + (ln >> 4) * 8;
    kbA[i] = kb; lnA[i] = ln;
    wbase[i] = (i < 2) ? (l > 0 ? Widx(l - 1, m, k0 >> 1) : 0)
                       : Widx(l, m, (k0 - 256) >> 1);
  }

  for (int t = 0; t < 64; ++t) {
    const int slotCur = t & 1, slotPrev = (t + 1) & 1;
    const unsigned short tagIn = (unsigned short)t;        // h(l-1,t)
    const unsigned short tagOwn = (unsigned short)(t - 1); // h(l,t-1); t=0 -> 0xFFFF

    // ---- l==0: input half straight from x (static, untagged) ----
    if (l == 0) {
#pragma unroll
      for (int i = 0; i < 2; ++i) {
        const int kb = kbA[i], ln = lnA[i];
        const int m = ln & 15, k0 = kb * 32 + (ln >> 4) * 8;
        const float* xs = x + ((size_t)m * 64 + t) * 256 + k0;
        half8 hv;
#pragma unroll
        for (int jj = 0; jj < 8; ++jj) hv[jj] = (_Float16)xs[jj];
        *(half8*)&aLds[(size_t)(kb * 64 + ln) * 8] = hv;
      }
    }

    // ---- poll+stage: each thread owns 16 words (bits 0-7: input half, 8-15: own) ----
    unsigned pend = (l == 0) ? 0xFF00u : 0xFFFFu;
    bool bp = !(tid == 0 && l < 63 && t >= 2);  // backpressure: only tid0 checks
    int round = 0;
    while (pend || !bp) {
      bool fast = true;
      if (round >= 2 && l > 0 && (pend & 0x00FFu)) {
        // producer far behind? poll 1 word instead of hammering 16 (fill-phase gate)
        int pl = __hip_atomic_load(&prog[(l - 1) * 4 + r], __ATOMIC_RELAXED, SCOPE);
        fast = (pl >= t);
      }
      if (fast && pend) {
        unsigned long long wv_[16];
#pragma unroll
        for (int i = 0; i < 4; ++i) {
          const unsigned long long* sp =
              Hw + ((i < 2 ? slotCur : slotPrev) ? SLOT_STRIDE : 0) + wbase[i];
#pragma unroll
          for (int j = 0; j < 4; ++j) {
            const int b_ = i * 4 + j;
            if ((pend >> b_) & 1u)
              wv_[b_] = __hip_atomic_load(sp + j, __ATOMIC_RELAXED, SCOPE);
          }
        }
#pragma unroll
        for (int i = 0; i < 4; ++i) {
          unsigned* dp = (unsigned*)&aLds[(size_t)(kbA[i] * 64 + lnA[i]) * 8];
          const unsigned short exp_ = (i < 2) ? tagIn : tagOwn;
#pragma unroll
          for (int j = 0; j < 4; ++j) {
            const int b_ = i * 4 + j;
            if ((pend >> b_) & 1u) {
              const unsigned long long wd = wv_[b_];
              if ((unsigned short)(wd >> 32) == exp_) {
                dp[j] = (unsigned)wd;  // low 32b = two f16 h values
                pend &= ~(1u << b_);
              }
            }
          }
        }
      }
      if (!bp) {
        const int need = t - 2;
        int p0 = __hip_atomic_load(&prog[(l + 1) * 4 + 0], __ATOMIC_RELAXED, SCOPE);
        int p1 = __hip_atomic_load(&prog[(l + 1) * 4 + 1], __ATOMIC_RELAXED, SCOPE);
        int p2 = __hip_atomic_load(&prog[(l + 1) * 4 + 2], __ATOMIC_RELAXED, SCOPE);
        int p3 = __hip_atomic_load(&prog[(l + 1) * 4 + 3], __ATOMIC_RELAXED, SCOPE);
        bp = (p0 >= need) && (p1 >= need) && (p2 >= need) && (p3 >= need);
      }
      if (pend || !bp) {
        ++round;
        if (round > 4000000) break;  // hang guard: fail wrong, not dead
        if (fast) __builtin_amdgcn_s_sleep(1);
        else      __builtin_amdgcn_s_sleep(16);
      }
    }
    __syncthreads();
    // staging complete -> publish progress (relaxed; enables producers' overwrite)
    if (tid == 0) __hip_atomic_store(&prog[wg], t, __ATOMIC_RELAXED, SCOPE);

    // ---- GEMM: z[16 x 256slice] = A[16x512] * Wslice[512x256] (unchanged) ----
    f32x4 acc[4] = {{0.f, 0.f, 0.f, 0.f}, {0.f, 0.f, 0.f, 0.f},
                    {0.f, 0.f, 0.f, 0.f}, {0.f, 0.f, 0.f, 0.f}};
#pragma unroll
    for (int kb = 0; kb < 16; ++kb) {
      half8 a = *(const half8*)&aLds[(kb * 64 + lane) * 8];
#pragma unroll
      for (int q = 0; q < 4; ++q)
        acc[q] = __builtin_amdgcn_mfma_f32_16x16x32_f16(a, wreg[q * 16 + kb], acc[q], 0, 0, 0);
    }

    // ---- z -> LDS transpose (unchanged) ----
#pragma unroll
    for (int q = 0; q < 4; ++q) {
      const int nl = (wv * 4 + q) * 16 + (lane & 15);
      const int m0 = (lane >> 4) * 4;
#pragma unroll
      for (int rg = 0; rg < 4; ++rg) zLds[(m0 + rg) * 260 + nl] = acc[q][rg];
    }
    __syncthreads();

    // ---- LSTM epilogue (unchanged) ----
#pragma unroll
    for (int bb = 0; bb < 4; ++bb) {
      const int b = b4 * 4 + bb;
      f32x4 zg = *(const f32x4*)&zLds[b * 260 + hu * 4];  // (i,j,f,o)
      const float iv = zg[0] + bi_, jv = zg[1] + bj_;
      const float fv = zg[2] + bf_, ov = zg[3] + bo_;
      const float nc = sigm(fv + 1.0f) * creg[bb] + sigm(iv) * tanh_(jv);
      const float nh = sigm(ov) * tanh_(nc);
      creg[bb] = nc;
      union { _Float16 f; unsigned short s; } cv;
      cv.f = (_Float16)nh;
      hLds[b * 64 + hu] = cv.s;
      if (l == 63) out[((size_t)b * 64 + t) * 256 + gu] = nh;
    }
    __syncthreads();  // hLds consistent for repack (no drain semantics needed)

    // ---- publish: tagged words, fire-and-forget (no fence, no flag) ----
    {
      const int b = tid >> 4, lw0 = (tid & 15) * 2;
#pragma unroll
      for (int q = 0; q < 2; ++q) {
        const int lw = lw0 + q, u0 = 2 * lw;
        unsigned lo = (unsigned)hLds[b * 64 + u0] | ((unsigned)hLds[b * 64 + u0 + 1] << 16);
        unsigned long long wd =
            (unsigned long long)lo | ((unsigned long long)tagIn << 32);
        __hip_atomic_store(Hw + (slotCur ? SLOT_STRIDE : 0) + Widx(l, b, r * 32 + lw),
                           wd, __ATOMIC_RELAXED, SCOPE);
      }
    }
    // no trailing barrier: next iter's staging barrier orders aLds/hLds reuse
  }
}

extern "C" void kernel_launch(void* const* d_in, const int* in_sizes, int n_in,
                              void* d_out, int out_size, void* d_ws,
                              size_t ws_size, hipStream_t stream) {
  const float* x          = (const float*)d_in[0];
  const float* init_state = (const float*)d_in[1];
  const float* W          = (const float*)d_in[2];
  const float* bias       = (const float*)d_in[3];
  float* out = (float*)d_out;
  char* ws   = (char*)d_ws;

  init_ws<<<256, 256, 0, stream>>>(init_state, ws);
  lstm_mfma<<<256, 256, 0, stream>>>(x, init_state, W, bias, out, ws);
}

// Round 2
// 797.142 us; speedup vs baseline: 1.0201x; 1.0201x over previous
//
#include <hip/hip_runtime.h>

typedef _Float16 half8 __attribute__((ext_vector_type(8)));
typedef float f32x4 __attribute__((ext_vector_type(4)));

#define SC_AGENT __HIP_MEMORY_SCOPE_AGENT
#define SC_WG    __HIP_MEMORY_SCOPE_WORKGROUP

// Problem: B=16, T=64, L=64, H=256. K=2H=512, N=4H=1024.
//
// Tag-in-word protocol (round 1) + XCD-affinity placement (this round):
//   h published as 8B words [h0 f16 | h1 f16 | tag=t | 0] via agent-scope
//   relaxed atomic store (sc0+sc1 write-through -> visible in home L2 + IC).
//   Consumers poll their own words; tag match <=> payload valid.
//
//   Placement: blockIdx round-robins across 8 XCDs (wg%8 = XCD, measured).
//   Remap wg -> (l,r) so layers 8k..8k+7 (32 WGs) share XCD k:
//     l = ((wg&7)<<3) | (wg>>5),  r = (wg>>3)&3
//   => sibling exchange + 56/63 layer hops are same-L2; 7 hops cross XCDs.
//
//   Two-tier polling: fast rounds use WORKGROUP-scope atomic loads (cacheable,
//   L1/L2-served ~100-300ns); every 2nd round escalates to AGENT scope (IC,
//   guaranteed fresh). Tags make stale cache hits benign (retry); escalation
//   bounds detection lag regardless of actual WG->XCD placement, so
//   correctness does NOT depend on the placement heuristic (G16-safe).
//
//   Backpressure: prog[wg] = latest staged t (agent store). Producer may
//   overwrite slot t&1 (step t-2) once all 4 consumer WGs have prog >= t-2.
//
// ws layout: prog[256] int at 0; Hw at 64KB: 2 slots * 64l * 16b * 128w * 8B = 2MB.
constexpr size_t OFF_PROG = 0;
constexpr size_t OFF_H    = 65536;
constexpr size_t SLOT_STRIDE = (size_t)64 * 16 * 128;  // words per slot

__device__ __forceinline__ size_t Widx(int l, int b, int wi) {
  return ((size_t)l * 16 + b) * 128 + wi;
}
__device__ __forceinline__ int wgid(int l, int r) {
  return (((l & 7) * 4 + r) << 3) | (l >> 3);  // inverse of the (l,r) remap
}
__device__ __forceinline__ float sigm(float v) { return 1.0f / (1.0f + __expf(-v)); }
__device__ __forceinline__ float tanh_(float v) { return 1.0f - 2.0f / (__expf(2.0f * v) + 1.0f); }

// ---------------- init: prog=-1, slot0 tags invalid, slot1 = h(l,-1) tag 0xFFFF ----
__global__ void init_ws(const float* __restrict__ init_state, char* ws) {
  int* prog = (int*)(ws + OFF_PROG);
  unsigned long long* Hw = (unsigned long long*)(ws + OFF_H);
  const int tid = blockIdx.x * 256 + threadIdx.x;  // 65536 threads
  if (tid < 256) prog[tid] = -1;
  for (int e = tid; e < 64 * 16 * 128; e += 65536) {
    const int wi = e & 127, b = (e >> 7) & 15, l = e >> 11;
    Hw[Widx(l, b, wi)] = 0xFFFE00000000ULL;  // slot0: tag 0xFFFE (never matches)
    union { _Float16 f; unsigned short s; } h0, h1;
    h0.f = (_Float16)init_state[((l * 2 + 1) * 16 + b) * 256 + 2 * wi];
    h1.f = (_Float16)init_state[((l * 2 + 1) * 16 + b) * 256 + 2 * wi + 1];
    Hw[SLOT_STRIDE + Widx(l, b, wi)] =
        (unsigned long long)h0.s | ((unsigned long long)h1.s << 16) | (0xFFFFULL << 32);
  }
}

// ---------------- main: 256 WGs; XCD-affine (l,r) from wg ----------------
__global__ __launch_bounds__(256, 1) void lstm_mfma(
    const float* __restrict__ x, const float* __restrict__ init_state,
    const float* __restrict__ W, const float* __restrict__ bias,
    float* __restrict__ out, char* ws) {
  int* prog = (int*)(ws + OFF_PROG);
  unsigned long long* Hw = (unsigned long long*)(ws + OFF_H);

  const int tid = threadIdx.x;
  const int wg = blockIdx.x;
  const int l = ((wg & 7) << 3) | (wg >> 5);  // layers 8k..8k+7 share XCD k
  const int r = (wg >> 3) & 3;
  const int wv = tid >> 6, lane = tid & 63;

  __shared__ alignas(16) _Float16 aLds[16 * 64 * 8];  // A-frags: [kb][lane][8], 16 KB
  __shared__ alignas(16) float zLds[16 * 260];        // z transpose, 16.6 KB
  __shared__ unsigned short hLds[16 * 64];            // nh f16 bits, 2 KB

  // ---- W slice -> registers (unchanged) ----
  half8 wreg[64];
#pragma unroll
  for (int q = 0; q < 4; ++q) {
    const int nl = (wv * 4 + q) * 16 + (lane & 15);
    const int col = (nl & 3) * 256 + r * 64 + (nl >> 2);
#pragma unroll
    for (int kb = 0; kb < 16; ++kb) {
      const int k0 = kb * 32 + (lane >> 4) * 8;
      const float* src = W + (size_t)k0 * 1024 + col;
      half8 hv;
#pragma unroll
      for (int jj = 0; jj < 8; ++jj) hv[jj] = (_Float16)src[(size_t)jj * 1024];
      wreg[q * 16 + kb] = hv;
    }
  }

  // ---- per-thread epilogue identity (unchanged) ----
  const int hu = tid & 63, b4 = tid >> 6;
  const int gu = r * 64 + hu;
  float creg[4];
#pragma unroll
  for (int bb = 0; bb < 4; ++bb)
    creg[bb] = init_state[((l * 2 + 0) * 16 + (b4 * 4 + bb)) * 256 + gu];
  const float bi_ = bias[0 * 256 + gu], bj_ = bias[1 * 256 + gu];
  const float bf_ = bias[2 * 256 + gu], bo_ = bias[3 * 256 + gu];

  // ---- staging entry invariants ----
  int kbA[4], lnA[4];
  size_t wbase[4];
#pragma unroll
  for (int i = 0; i < 4; ++i) {
    const int e = i * 256 + tid, kb = e >> 6, ln = e & 63;
    const int m = ln & 15, k0 = kb * 32 + (ln >> 4) * 8;
    kbA[i] = kb; lnA[i] = ln;
    wbase[i] = (i < 2) ? (l > 0 ? Widx(l - 1, m, k0 >> 1) : 0)
                       : Widx(l, m, (k0 - 256) >> 1);
  }

  // ---- sync addresses (remapped wg indices) ----
  int* const progIn = &prog[wgid(l > 0 ? l - 1 : 0, r)];
  int* const bpp0 = &prog[wgid(l < 63 ? l + 1 : 63, 0)];
  int* const bpp1 = &prog[wgid(l < 63 ? l + 1 : 63, 1)];
  int* const bpp2 = &prog[wgid(l < 63 ? l + 1 : 63, 2)];
  int* const bpp3 = &prog[wgid(l < 63 ? l + 1 : 63, 3)];

  for (int t = 0; t < 64; ++t) {
    const int slotCur = t & 1, slotPrev = (t + 1) & 1;
    const unsigned short tagIn = (unsigned short)t;
    const unsigned short tagOwn = (unsigned short)(t - 1);  // t=0 -> 0xFFFF

    if (l == 0) {
#pragma unroll
      for (int i = 0; i < 2; ++i) {
        const int kb = kbA[i], ln = lnA[i];
        const int m = ln & 15, k0 = kb * 32 + (ln >> 4) * 8;
        const float* xs = x + ((size_t)m * 64 + t) * 256 + k0;
        half8 hv;
#pragma unroll
        for (int jj = 0; jj < 8; ++jj) hv[jj] = (_Float16)xs[jj];
        *(half8*)&aLds[(size_t)(kb * 64 + ln) * 8] = hv;
      }
    }

    // ---- poll+stage: WG-scope (cached) rounds, agent escalation on odd rounds ----
    unsigned pend = (l == 0) ? 0xFF00u : 0xFFFFu;
    bool bp = !(tid == 0 && l < 63 && t >= 2);
    int round = 0;
    while (pend || !bp) {
      const bool esc = (round & 1) != 0;
      // fill-phase damping: producer layer far behind -> poll 1 cached word only
      bool damp = false;
      if (round >= 8 && l > 0 && (pend & 0x00FFu)) {
        int pl = ((round & 7) == 1)
                     ? __hip_atomic_load(progIn, __ATOMIC_RELAXED, SC_AGENT)
                     : __hip_atomic_load(progIn, __ATOMIC_RELAXED, SC_WG);
        damp = (pl < t);
      }
      if (pend && !damp) {
        unsigned long long wv_[16];
#pragma unroll
        for (int i = 0; i < 4; ++i) {
          const unsigned long long* sp =
              Hw + ((i < 2 ? slotCur : slotPrev) ? SLOT_STRIDE : 0) + wbase[i];
#pragma unroll
          for (int j = 0; j < 4; ++j) {
            const int b_ = i * 4 + j;
            if ((pend >> b_) & 1u)
              wv_[b_] = esc ? __hip_atomic_load(sp + j, __ATOMIC_RELAXED, SC_AGENT)
                            : __hip_atomic_load(sp + j, __ATOMIC_RELAXED, SC_WG);
          }
        }
#pragma unroll
        for (int i = 0; i < 4; ++i) {
          unsigned* dp = (unsigned*)&aLds[(size_t)(kbA[i] * 64 + lnA[i]) * 8];
          const unsigned short exp_ = (i < 2) ? tagIn : tagOwn;
#pragma unroll
          for (int j = 0; j < 4; ++j) {
            const int b_ = i * 4 + j;
            if ((pend >> b_) & 1u) {
              const unsigned long long wd = wv_[b_];
              if ((unsigned short)(wd >> 32) == exp_) {
                dp[j] = (unsigned)wd;
                pend &= ~(1u << b_);
              }
            }
          }
        }
      }
      if (!bp) {
        const int need = t - 2;
        int p0, p1, p2, p3;
        if (esc) {
          p0 = __hip_atomic_load(bpp0, __ATOMIC_RELAXED, SC_AGENT);
          p1 = __hip_atomic_load(bpp1, __ATOMIC_RELAXED, SC_AGENT);
          p2 = __hip_atomic_load(bpp2, __ATOMIC_RELAXED, SC_AGENT);
          p3 = __hip_atomic_load(bpp3, __ATOMIC_RELAXED, SC_AGENT);
        } else {
          p0 = __hip_atomic_load(bpp0, __ATOMIC_RELAXED, SC_WG);
          p1 = __hip_atomic_load(bpp1, __ATOMIC_RELAXED, SC_WG);
          p2 = __hip_atomic_load(bpp2, __ATOMIC_RELAXED, SC_WG);
          p3 = __hip_atomic_load(bpp3, __ATOMIC_RELAXED, SC_WG);
        }
        bp = (p0 >= need) && (p1 >= need) && (p2 >= need) && (p3 >= need);
      }
      if (pend || !bp) {
        ++round;
        if (round > 2000000) break;  // hang guard: fail visibly, not dead
        if (damp) __builtin_amdgcn_s_sleep(4);
      }
    }
    __syncthreads();
    if (tid == 0) __hip_atomic_store(&prog[wg], t, __ATOMIC_RELAXED, SC_AGENT);

    // ---- GEMM (unchanged) ----
    f32x4 acc[4] = {{0.f, 0.f, 0.f, 0.f}, {0.f, 0.f, 0.f, 0.f},
                    {0.f, 0.f, 0.f, 0.f}, {0.f, 0.f, 0.f, 0.f}};
#pragma unroll
    for (int kb = 0; kb < 16; ++kb) {
      half8 a = *(const half8*)&aLds[(kb * 64 + lane) * 8];
#pragma unroll
      for (int q = 0; q < 4; ++q)
        acc[q] = __builtin_amdgcn_mfma_f32_16x16x32_f16(a, wreg[q * 16 + kb], acc[q], 0, 0, 0);
    }

    // ---- z -> LDS transpose (unchanged) ----
#pragma unroll
    for (int q = 0; q < 4; ++q) {
      const int nl = (wv * 4 + q) * 16 + (lane & 15);
      const int m0 = (lane >> 4) * 4;
#pragma unroll
      for (int rg = 0; rg < 4; ++rg) zLds[(m0 + rg) * 260 + nl] = acc[q][rg];
    }
    __syncthreads();

    // ---- LSTM epilogue (unchanged) ----
#pragma unroll
    for (int bb = 0; bb < 4; ++bb) {
      const int b = b4 * 4 + bb;
      f32x4 zg = *(const f32x4*)&zLds[b * 260 + hu * 4];  // (i,j,f,o)
      const float iv = zg[0] + bi_, jv = zg[1] + bj_;
      const float fv = zg[2] + bf_, ov = zg[3] + bo_;
      const float nc = sigm(fv + 1.0f) * creg[bb] + sigm(iv) * tanh_(jv);
      const float nh = sigm(ov) * tanh_(nc);
      creg[bb] = nc;
      union { _Float16 f; unsigned short s; } cv;
      cv.f = (_Float16)nh;
      hLds[b * 64 + hu] = cv.s;
      if (l == 63) out[((size_t)b * 64 + t) * 256 + gu] = nh;
    }
    __syncthreads();

    // ---- publish: tagged words, agent write-through (home-L2 + IC) ----
    {
      const int b = tid >> 4, lw0 = (tid & 15) * 2;
#pragma unroll
      for (int q = 0; q < 2; ++q) {
        const int lw = lw0 + q, u0 = 2 * lw;
        unsigned lo = (unsigned)hLds[b * 64 + u0] | ((unsigned)hLds[b * 64 + u0 + 1] << 16);
        unsigned long long wd =
            (unsigned long long)lo | ((unsigned long long)tagIn << 32);
        __hip_atomic_store(Hw + (slotCur ? SLOT_STRIDE : 0) + Widx(l, b, r * 32 + lw),
                           wd, __ATOMIC_RELAXED, SC_AGENT);
      }
    }
    // no trailing barrier: next iter's staging barrier orders aLds/hLds reuse
  }
}

extern "C" void kernel_launch(void* const* d_in, const int* in_sizes, int n_in,
                              void* d_out, int out_size, void* d_ws,
                              size_t ws_size, hipStream_t stream) {
  const float* x          = (const float*)d_in[0];
  const float* init_state = (const float*)d_in[1];
  const float* W          = (const float*)d_in[2];
  const float* bias       = (const float*)d_in[3];
  float* out = (float*)d_out;
  char* ws   = (char*)d_ws;

  init_ws<<<256, 256, 0, stream>>>(init_state, ws);
  lstm_mfma<<<256, 256, 0, stream>>>(x, init_state, W, bias, out, ws);
}